// Round 1
// baseline (2467.050 us; speedup 1.0000x reference)
//
#include <hip/hip_runtime.h>
#include <math.h>

#define D 64

// ---------------- gather rows: out[i] = src[idx[i]] (row of 64 floats) ----------------
__global__ __launch_bounds__(256) void k_gather_rows(const float* __restrict__ src,
                                                     const int* __restrict__ idx,
                                                     float* __restrict__ out, int n) {
    int i = blockIdx.x * blockDim.x + threadIdx.x;
    if (i >= n * D) return;
    int r = i >> 6, c = i & 63;
    out[i] = src[(size_t)idx[r] * D + c];
}

// ---------------- out[N,64] = in[N,64] @ W[64,64] ----------------
__global__ __launch_bounds__(256) void k_transform(const float* __restrict__ in,
                                                   const float* __restrict__ W,
                                                   float* __restrict__ out, int n) {
    __shared__ float Ws[D * D];
    __shared__ float rows[4][D];
    int t = threadIdx.x;
#pragma unroll
    for (int i = 0; i < 16; ++i) Ws[i * 256 + t] = W[i * 256 + t];
    int r = blockIdx.x * 4 + (t >> 6);
    int c = t & 63;
    if (r < n) rows[t >> 6][c] = in[r * D + c];
    __syncthreads();
    if (r >= n) return;
    const float* rw = rows[t >> 6];
    float acc = 0.f;
#pragma unroll
    for (int d = 0; d < D; ++d) acc += rw[d] * Ws[d * D + c];
    out[r * D + c] = acc;
}

// ---------------- fused edge score + softmax-accumulate (one wave per edge) ----------------
// e    = sum_d (cos(t*efreq+ephase) + srcF[src]) * dstF[dst] / 8
// ex   = exp(e)           (max-shift skipped: softmax shift-invariant, |e| tiny)
// agg[dst]   += ex * (srcF[src] + cos(t*kfreq+kphase))
// denom[dst] += ex
__global__ __launch_bounds__(256) void k_edge(const float* __restrict__ srcF,
                                              const float* __restrict__ dstF,
                                              const int* __restrict__ esrc,
                                              const int* __restrict__ edst,
                                              const float* __restrict__ et,
                                              const float* __restrict__ efreq,
                                              const float* __restrict__ ephase,
                                              const float* __restrict__ kfreq,
                                              const float* __restrict__ kphase,
                                              float* __restrict__ agg,
                                              float* __restrict__ denom, int E) {
    int e = blockIdx.x * 4 + (threadIdx.x >> 6);
    if (e >= E) return;
    int lane = threadIdx.x & 63;
    int s = esrc[e], dd = edst[e];
    float t = et[e];
    float sv = srcF[s * D + lane];
    float dv = dstF[dd * D + lane];
    float te = __cosf(fmaf(t, efreq[lane], ephase[lane]));
    float p = (te + sv) * dv;
#pragma unroll
    for (int off = 32; off; off >>= 1) p += __shfl_xor(p, off);
    float ex = __expf(p * 0.125f);
    float tek = __cosf(fmaf(t, kfreq[lane], kphase[lane]));
    unsafeAtomicAdd(&agg[dd * D + lane], ex * (sv + tek));
    if (lane == 0) unsafeAtomicAdd(&denom[dd], ex);
}

// ---------------- h = elu(concat([agg/denom, h]) @ W2[128,64]), in place ----------------
__global__ __launch_bounds__(256) void k_update(float* __restrict__ h,
                                                const float* __restrict__ agg,
                                                const float* __restrict__ denom,
                                                const float* __restrict__ W2, int n) {
    __shared__ float Ws[2 * D * D];  // 32 KB
    __shared__ float rows[4][2 * D];
    int t = threadIdx.x;
#pragma unroll
    for (int i = 0; i < 32; ++i) Ws[i * 256 + t] = W2[i * 256 + t];
    int r = blockIdx.x * 4 + (t >> 6);
    int c = t & 63;
    if (r < n) {
        float dn = denom[r];
        float inv = dn > 0.f ? 1.f / dn : 0.f;  // empty segment -> agg row = 0
        rows[t >> 6][c] = agg[r * D + c] * inv;
        rows[t >> 6][D + c] = h[r * D + c];
    }
    __syncthreads();
    if (r >= n) return;
    const float* rw = rows[t >> 6];
    float acc = 0.f;
#pragma unroll
    for (int d = 0; d < 2 * D; ++d) acc += rw[d] * Ws[d * D + c];
    h[r * D + c] = acc > 0.f ? acc : __expf(acc) - 1.f;  // elu
}

// ---------------- feat[b, colOff:colOff+64] = h[idx[b]] ----------------
__global__ __launch_bounds__(256) void k_gather_feat(const float* __restrict__ h,
                                                     const int* __restrict__ idx,
                                                     float* __restrict__ feat, int B,
                                                     int colOff, int FW) {
    int i = blockIdx.x * blockDim.x + threadIdx.x;
    if (i >= B * D) return;
    int b = i >> 6, c = i & 63;
    feat[(size_t)b * FW + colOff + c] = h[(size_t)idx[b] * D + c];
}

// ---------------- out[b] = relu((feat[b] @ uW) @ dW + db), one block (64 thr) per row ----
__global__ __launch_bounds__(64) void k_final(const float* __restrict__ feat,
                                              const float* __restrict__ uW,
                                              const float* __restrict__ dW,
                                              const float* __restrict__ db,
                                              float* __restrict__ out, int B, int FW) {
    __shared__ float fr[256];
    __shared__ float un[D];
    int b = blockIdx.x;
    int c = threadIdx.x;
    for (int i = c; i < FW; i += 64) fr[i] = feat[(size_t)b * FW + i];
    __syncthreads();
    float acc = 0.f;
    for (int d = 0; d < FW; ++d) acc += fr[d] * uW[d * D + c];
    un[c] = acc;
    __syncthreads();
    if (c < 3) {
        float o = db[c];
#pragma unroll
        for (int d = 0; d < D; ++d) o += un[d] * dW[d * 3 + c];
        out[b * 3 + c] = o > 0.f ? o : 0.f;
    }
}

extern "C" void kernel_launch(void* const* d_in, const int* in_sizes, int n_in,
                              void* d_out, int out_size, void* d_ws, size_t ws_size,
                              hipStream_t stream) {
    const float* user_emb = (const float*)d_in[0];
    const float* item_emb = (const float*)d_in[1];
    const float* Wu       = (const float*)d_in[2];
    const float* Wi       = (const float*)d_in[3];
    const float* Wuu      = (const float*)d_in[4];
    const float* Wii      = (const float*)d_in[5];
    const float* u_freq   = (const float*)d_in[6];
    const float* u_phase  = (const float*)d_in[7];
    const float* uk_freq  = (const float*)d_in[8];
    const float* uk_phase = (const float*)d_in[9];
    const float* i_freq   = (const float*)d_in[10];
    const float* i_phase  = (const float*)d_in[11];
    const float* ik_freq  = (const float*)d_in[12];
    const float* ik_phase = (const float*)d_in[13];
    const float* unified_W = (const float*)d_in[14];
    const float* dense_W   = (const float*)d_in[15];
    const float* dense_b   = (const float*)d_in[16];
    const float* by_time   = (const float*)d_in[17];
    const float* pby_time  = (const float*)d_in[18];
    const int* user_id   = (const int*)d_in[19];
    const int* item_id   = (const int*)d_in[20];
    const int* by_src    = (const int*)d_in[21];
    const int* by_dst    = (const int*)d_in[22];
    const int* pby_src   = (const int*)d_in[23];
    const int* pby_dst   = (const int*)d_in[24];
    const int* user_index = (const int*)d_in[25];
    const int* last_item_index = (const int*)d_in[26];

    const int NU = in_sizes[19];
    const int NI = in_sizes[20];
    const int E  = in_sizes[21];
    const int B  = in_sizes[25];
    const int L  = in_sizes[2] / (D * D);
    const int FW = (L + 1) * D;

    // workspace layout (floats); zero-region [agg_u|agg_i|denom_u|denom_i] is contiguous
    float* w = (float*)d_ws;
    float* agg_u   = w; w += (size_t)NU * D;
    float* agg_i   = w; w += (size_t)NI * D;
    float* denom_u = w; w += NU;
    float* denom_i = w; w += NI;
    size_t zero_bytes = (size_t)((char*)w - (char*)d_ws);
    float* uh      = w; w += (size_t)NU * D;
    float* ih      = w; w += (size_t)NI * D;
    float* user_h  = w; w += (size_t)NU * D;
    float* item_h  = w; w += (size_t)NI * D;
    float* feat    = w; w += (size_t)B * FW;

    k_gather_rows<<<(NU * D + 255) / 256, 256, 0, stream>>>(user_emb, user_id, user_h, NU);
    k_gather_rows<<<(NI * D + 255) / 256, 256, 0, stream>>>(item_emb, item_id, item_h, NI);

    for (int l = 0; l < L; ++l) {
        hipMemsetAsync(d_ws, 0, zero_bytes, stream);
        k_transform<<<(NU + 3) / 4, 256, 0, stream>>>(user_h, Wu + l * D * D, uh, NU);
        k_transform<<<(NI + 3) / 4, 256, 0, stream>>>(item_h, Wi + l * D * D, ih, NI);
        // 'by': item -> user
        k_edge<<<(E + 3) / 4, 256, 0, stream>>>(ih, uh, by_src, by_dst, by_time,
                                                u_freq + l * D, u_phase + l * D,
                                                uk_freq + l * D, uk_phase + l * D,
                                                agg_u, denom_u, E);
        // 'pby': user -> item
        k_edge<<<(E + 3) / 4, 256, 0, stream>>>(uh, ih, pby_src, pby_dst, pby_time,
                                                i_freq + l * D, i_phase + l * D,
                                                ik_freq + l * D, ik_phase + l * D,
                                                agg_i, denom_i, E);
        k_update<<<(NU + 3) / 4, 256, 0, stream>>>(user_h, agg_u, denom_u,
                                                   Wuu + (size_t)l * 2 * D * D, NU);
        k_update<<<(NI + 3) / 4, 256, 0, stream>>>(item_h, agg_i, denom_i,
                                                   Wii + (size_t)l * 2 * D * D, NI);
        k_gather_feat<<<(B * D + 255) / 256, 256, 0, stream>>>(user_h, user_index, feat, B,
                                                               l * D, FW);
    }
    k_gather_feat<<<(B * D + 255) / 256, 256, 0, stream>>>(item_h, last_item_index, feat, B,
                                                           L * D, FW);
    k_final<<<B, 64, 0, stream>>>(feat, unified_W, dense_W, dense_b, (float*)d_out, B, FW);
}